// Round 15
// baseline (73.904 us; speedup 1.0000x reference)
//
#include <hip/hip_runtime.h>
#include <hip/hip_bf16.h>

// TreeEncoder B=64,N=8192,F=H=64,L=2 — fp16 MFMA v15: skewed dual-stream.
// Evidence: occupancy+3 neutral (v14), barrier-halving hurt (v13) -> residual
// is lockstep-phase pipe serialization. v15: 512-thr blocks = 2 independent
// 4-wave streams on separate LDS planes, offset half a pipeline, so every
// barrier interval mixes MFMA-heavy waves with gate/VALU-heavy waves on the
// same SIMD (wave role diversity, the T3/T5 mechanism). 2.25 barriers/tile,
// 4 waves/SIMD (2 blk/CU @ 50KB LDS, VGPR<=128). v12 math byte-identical.
// Skew:  pre: A:C(a0) | A:E(a0) B:C(b0) |
// loop k: A:G0(ak) B:E(bk) | A:G1 B:G0 | A:C(ak+1) B:G1 | A:E(ak+1) B:C(bk+1) |

typedef __attribute__((ext_vector_type(4))) float f32x4;
typedef __attribute__((ext_vector_type(8))) short s16x8;
typedef __attribute__((ext_vector_type(2))) unsigned u32x2;
typedef __attribute__((ext_vector_type(4))) unsigned u32x4;
typedef _Float16 h2 __attribute__((ext_vector_type(2)));

__device__ __forceinline__ unsigned short f2h(float f) {  // RNE f32->fp16
    _Float16 h = (_Float16)f;
    return __builtin_bit_cast(unsigned short, h);
}
__device__ __forceinline__ h2 pkrtz(float a, float b) {   // v_cvt_pkrtz
    return __builtin_bit_cast(h2, __builtin_amdgcn_cvt_pkrtz(a, b));
}
__device__ __forceinline__ unsigned pk2(float a, float b) {
    return __builtin_bit_cast(unsigned, __builtin_amdgcn_cvt_pkrtz(a, b));
}
__device__ __forceinline__ h2 pfma(h2 a, h2 b, h2 c) {    // v_pk_fma_f16
    return __builtin_elementwise_fma(a, b, c);
}
#define H2C(v) h2{(_Float16)(v), (_Float16)(v)}

// h = sigmoid(z1) * tanh( sigmoid(z0) * tanh(z2) ), packed fp16, no division.
__device__ __forceinline__ h2 gate2(h2 z0, h2 z1, h2 z2) {
    const h2 C3 = H2C(-0.33333334f), C5 = H2C(0.13333334f), C7 = H2C(-0.05396825f);
    const h2 Q1 = H2C(0.25f), Q3 = H2C(-0.020833334f), Q5 = H2C(0.0020833334f);
    const h2 ONE = H2C(1.0f), HALF = H2C(0.5f);
    h2 s0 = z0 * z0, s1 = z1 * z1, s2 = z2 * z2;
    h2 sg0 = pfma(z0, pfma(pfma(Q5, s0, Q3), s0, Q1), HALF);
    h2 sg1 = pfma(z1, pfma(pfma(Q5, s1, Q3), s1, Q1), HALF);
    h2 t2  = z2 * pfma(pfma(pfma(C7, s2, C5), s2, C3), s2, ONE);
    h2 c   = sg0 * t2;
    h2 sc  = c * c;
    h2 th  = c * pfma(pfma(pfma(C7, sc, C5), sc, C3), sc, ONE);
    return sg1 * th;
}

// ---------------------------------------------------------------------------
// ws: u16 wfrag[56*512], fid = (mat*4 + wv)*2 + kk
//   lane l elem j = fp16( M[o][k] ), o = wv*16+(l&15), k = 8*(l>>4)+kk*32+j
//   mat0 = W_emb; mat 1+l*3+g = Wx[l][g].
// f32 wbias[7*64] @ byte 57344: mat0 = b_emb, else bW+bU.
// ---------------------------------------------------------------------------
__global__ void prep_weights(const float* __restrict__ W_emb,
                             const float* __restrict__ b_emb,
                             const float* __restrict__ Wx,
                             const float* __restrict__ bW,
                             const float* __restrict__ bU,
                             unsigned short* __restrict__ wfrag,
                             float* __restrict__ wbias) {
    int t = blockIdx.x * 256 + threadIdx.x;
    if (t < 448) {
        int mat = t >> 6, o = t & 63;
        wbias[t] = (mat == 0) ? b_emb[o] : (bW[(mat - 1) * 64 + o] + bU[(mat - 1) * 64 + o]);
    }
    if (t < 28672) {
        int j = t & 7, lane = (t >> 3) & 63, fid = t >> 9;
        int kk = fid & 1, wv = (fid >> 1) & 3, mat = fid >> 3;
        int o = wv * 16 + (lane & 15);
        int k = ((lane >> 4) << 3) + kk * 32 + j;
        float v = (mat == 0) ? W_emb[o * 64 + k] : Wx[(mat - 1) * 4096 + o * 64 + k];
        wfrag[t] = f2h(v);
    }
}

// ---------------------------------------------------------------------------
// Main: 1024 blocks x 512 thr. Stream s = tid>>8 (4 waves each) handles tiles
// blk*8 + s*4 + {0..3} on its own LDS planes. Batch = blk>>4.
// fp16 planes: element d of row n at u16 idx n*64 + (d ^ ((n&7)<<3)).
// MFMA maps (rounds 2-14 verified): A row o=w*16+(l&15), k=8*(l>>4)+kk*32+j;
// B col n=nt*16+(l&15); C row(dim)=w*16+4*(l>>4)+r, col(node)=nt*16+(l&15).
// ---------------------------------------------------------------------------
__global__ __launch_bounds__(512, 4) void tree_encoder_mfma(
        const float* __restrict__ tree,
        const unsigned short* __restrict__ wfrag,
        const float* __restrict__ wbias,
        float* __restrict__ out) {
    __shared__ unsigned short xh[2][4096];               // 16 KB
    __shared__ unsigned short hAp[2][4096], hBp[2][4096];// 32 KB
    __shared__ float biasL[448];                         // 1.75 KB
    const int tid = threadIdx.x;
    const int s = tid >> 8;                  // stream
    const int w = (tid >> 6) & 3, lane = tid & 63;
    const int lg = lane >> 4, lr = lane & 15;
    const int ltid = tid & 255;              // thread-in-stream

    for (int i = tid; i < 448; i += 512) biasL[i] = wbias[i];

    // persistent weight A-frags: 14 x s16x8 = 56 VGPR, PINNED (per wave, by w)
    s16x8 wA[14];
#pragma unroll
    for (int m = 0; m < 7; ++m)
#pragma unroll
        for (int kk = 0; kk < 2; ++kk)
            wA[m * 2 + kk] = *(const s16x8*)(wfrag + (((m * 4 + w) * 2 + kk) << 9) + lane * 8);
#pragma unroll
    for (int m = 0; m < 14; ++m) asm volatile("" : "+v"(wA[m]));  // no remat

    // loop-invariant LDS u16-offsets (plane-relative)
    int ro[4][2], wo[4];
#pragma unroll
    for (int nt = 0; nt < 4; ++nt) {
        const int n = nt * 16 + lr, sw = (n & 7) << 3;
        ro[nt][0] = (n << 6) + ((lg << 3) ^ sw);
        ro[nt][1] = (n << 6) + (((lg + 4) << 3) ^ sw);
        wo[nt] = (n << 6) + ((w * 16 + 4 * lg) ^ sw);
    }
    const int nc = ltid >> 2;                // conversion: node within tile
    const int qc = ltid & 3;                 // dim quarter (16 floats)
    const int co0 = (nc << 6) + (((2 * qc) ^ (nc & 7)) << 3);
    const int co1 = (nc << 6) + (((2 * qc + 1) ^ (nc & 7)) << 3);

    unsigned short* xPl = xh[s];
    unsigned short* hAPl = hAp[s];
    unsigned short* hBPl = hBp[s];

    float nsum[4] = {0.f, 0.f, 0.f, 0.f};
    const int tbase = blockIdx.x * 8 + s * 4;   // my stream's first tile

    f32x4 xp[4];
    auto PF = [&](int j) {  // prefetch tile tbase+j into xp
        const float* src = tree + ((size_t)(tbase + j) << 12) + (ltid << 4);
#pragma unroll
        for (int v = 0; v < 4; ++v) xp[v] = *(const f32x4*)(src + 4 * v);
    };
    auto CVT = [&]() {  // convert xp -> my x plane
        u32x4 v0, v1;
        v0[0] = pk2(xp[0][0], xp[0][1]); v0[1] = pk2(xp[0][2], xp[0][3]);
        v0[2] = pk2(xp[1][0], xp[1][1]); v0[3] = pk2(xp[1][2], xp[1][3]);
        v1[0] = pk2(xp[2][0], xp[2][1]); v1[1] = pk2(xp[2][2], xp[2][3]);
        v1[2] = pk2(xp[3][0], xp[3][1]); v1[3] = pk2(xp[3][2], xp[3][3]);
        *(u32x4*)&xPl[co0] = v0;
        *(u32x4*)&xPl[co1] = v1;
    };
    auto EMB = [&]() {
        const f32x4 be = *(const f32x4*)&biasL[w * 16 + 4 * lg];
        f32x4 acc[4];
#pragma unroll
        for (int nt = 0; nt < 4; ++nt) acc[nt] = be;
#pragma unroll
        for (int nt = 0; nt < 4; ++nt)
#pragma unroll
            for (int kk = 0; kk < 2; ++kk) {
                s16x8 b = *(const s16x8*)&xPl[ro[nt][kk]];
                acc[nt] = __builtin_amdgcn_mfma_f32_16x16x32_f16(wA[kk], b, acc[nt], 0, 0, 0);
            }
#pragma unroll
        for (int nt = 0; nt < 4; ++nt) {
            u32x2 p;
            p[0] = pk2(acc[nt][0], acc[nt][1]);
            p[1] = pk2(acc[nt][2], acc[nt][3]);
            *(u32x2*)&hAPl[wo[nt]] = p;
        }
    };
    auto L0 = [&]() {
        const f32x4 b0 = *(const f32x4*)&biasL[64 + w * 16 + 4 * lg];
        const f32x4 b1 = *(const f32x4*)&biasL[128 + w * 16 + 4 * lg];
        const f32x4 b2 = *(const f32x4*)&biasL[192 + w * 16 + 4 * lg];
#pragma unroll
        for (int nt = 0; nt < 4; ++nt) {
            f32x4 a0 = b0, a1 = b1, a2 = b2;
#pragma unroll
            for (int kk = 0; kk < 2; ++kk) {
                s16x8 b = *(const s16x8*)&hAPl[ro[nt][kk]];
                a0 = __builtin_amdgcn_mfma_f32_16x16x32_f16(wA[2 + kk], b, a0, 0, 0, 0);
                a1 = __builtin_amdgcn_mfma_f32_16x16x32_f16(wA[4 + kk], b, a1, 0, 0, 0);
                a2 = __builtin_amdgcn_mfma_f32_16x16x32_f16(wA[6 + kk], b, a2, 0, 0, 0);
            }
            h2 hlo = gate2(pkrtz(a0[0], a0[1]), pkrtz(a1[0], a1[1]), pkrtz(a2[0], a2[1]));
            h2 hhi = gate2(pkrtz(a0[2], a0[3]), pkrtz(a1[2], a1[3]), pkrtz(a2[2], a2[3]));
            u32x2 p;
            p[0] = __builtin_bit_cast(unsigned, hlo);
            p[1] = __builtin_bit_cast(unsigned, hhi);
            *(u32x2*)&hBPl[wo[nt]] = p;
        }
    };
    auto L1 = [&]() {
        const f32x4 b0 = *(const f32x4*)&biasL[256 + w * 16 + 4 * lg];
        const f32x4 b1 = *(const f32x4*)&biasL[320 + w * 16 + 4 * lg];
        const f32x4 b2 = *(const f32x4*)&biasL[384 + w * 16 + 4 * lg];
#pragma unroll
        for (int nt = 0; nt < 4; ++nt) {
            f32x4 a0 = b0, a1 = b1, a2 = b2;
#pragma unroll
            for (int kk = 0; kk < 2; ++kk) {
                s16x8 b = *(const s16x8*)&hBPl[ro[nt][kk]];
                a0 = __builtin_amdgcn_mfma_f32_16x16x32_f16(wA[8 + kk], b, a0, 0, 0, 0);
                a1 = __builtin_amdgcn_mfma_f32_16x16x32_f16(wA[10 + kk], b, a1, 0, 0, 0);
                a2 = __builtin_amdgcn_mfma_f32_16x16x32_f16(wA[12 + kk], b, a2, 0, 0, 0);
            }
            h2 hlo = gate2(pkrtz(a0[0], a0[1]), pkrtz(a1[0], a1[1]), pkrtz(a2[0], a2[1]));
            h2 hhi = gate2(pkrtz(a0[2], a0[3]), pkrtz(a1[2], a1[3]), pkrtz(a2[2], a2[3]));
            nsum[0] += (float)hlo[0];
            nsum[1] += (float)hlo[1];
            nsum[2] += (float)hhi[0];
            nsum[3] += (float)hhi[1];
        }
    };

    // ---- skewed pipeline ----
    PF(0);
    if (s == 0) { CVT(); PF(1); }            // A: C(a0)
    __syncthreads();
    if (s == 0) EMB(); else { CVT(); PF(1); }// A: E(a0)   B: C(b0)
    __syncthreads();
#pragma unroll 1
    for (int k = 0; k < 4; ++k) {
        if (s == 0) L0(); else EMB();        // A: G0(ak)  B: E(bk)
        __syncthreads();
        if (s == 0) L1(); else L0();         // A: G1(ak)  B: G0(bk)
        __syncthreads();
        if (s == 0) {                        // A: C(ak+1) B: G1(bk)
            if (k < 3) { CVT(); if (k < 2) PF(k + 2); }
        } else L1();
        __syncthreads();
        if (s == 0) {                        // A: E(ak+1) B: C(bk+1)
            if (k < 3) EMB();
        } else {
            if (k < 3) { CVT(); if (k < 2) PF(k + 2); }
        }
        __syncthreads();
    }

    // ---- reduce 16 node-columns per lane-group, emit ----
#pragma unroll
    for (int r = 0; r < 4; ++r) {
        float v = nsum[r];
        v += __shfl_xor(v, 1);
        v += __shfl_xor(v, 2);
        v += __shfl_xor(v, 4);
        v += __shfl_xor(v, 8);
        if (lr == 0)
            atomicAdd(&out[(blockIdx.x >> 4) * 64 + w * 16 + 4 * lg + r], v * (1.0f / 8192.0f));
    }
}

extern "C" void kernel_launch(void* const* d_in, const int* in_sizes, int n_in,
                              void* d_out, int out_size, void* d_ws, size_t ws_size,
                              hipStream_t stream) {
    const float* tree  = (const float*)d_in[0];
    const float* W_emb = (const float*)d_in[1];
    const float* b_emb = (const float*)d_in[2];
    const float* Wx    = (const float*)d_in[3];
    const float* bW    = (const float*)d_in[4];
    const float* bU    = (const float*)d_in[5];
    float* outp = (float*)d_out;
    unsigned short* wfrag = (unsigned short*)d_ws;
    float* wbias = (float*)((char*)d_ws + 57344);

    (void)hipMemsetAsync(d_out, 0, (size_t)out_size * sizeof(float), stream);
    prep_weights<<<112, 256, 0, stream>>>(W_emb, b_emb, Wx, bW, bU, wfrag, wbias);
    tree_encoder_mfma<<<1024, 512, 0, stream>>>(tree, wfrag, wbias, outp);
}

// Round 16
// 61.343 us; speedup vs baseline: 1.2048x; 1.2048x over previous
//
#include <hip/hip_runtime.h>
#include <hip/hip_bf16.h>

// TreeEncoder B=64,N=8192,F=H=64,L=2 — fp16 MFMA v16: v12 + packed-f32 gates.
// Evidence (15 rounds): only instruction-count cuts move this kernel
// (structural/scheduling changes all regressed). v16 cuts: (1) gates in
// packed f32 (v_pk_fma_f32; MFMA out already f32 -> deletes 22 pkrtz + 32
// nsum converts per wave-tile), (2) biases in 28 VGPRs (biasL LDS deleted),
// (3) d_out zeroing folded into prep (fillBuffer dispatch removed).
// Everything else = v12 (58.5us best).

typedef __attribute__((ext_vector_type(2))) float f32x2;
typedef __attribute__((ext_vector_type(4))) float f32x4;
typedef __attribute__((ext_vector_type(8))) short s16x8;
typedef __attribute__((ext_vector_type(2))) unsigned u32x2;
typedef __attribute__((ext_vector_type(4))) unsigned u32x4;

__device__ __forceinline__ unsigned short f2h(float f) {  // RNE f32->fp16
    _Float16 h = (_Float16)f;
    return __builtin_bit_cast(unsigned short, h);
}
__device__ __forceinline__ unsigned pk2(float a, float b) {  // v_cvt_pkrtz
    return __builtin_bit_cast(unsigned, __builtin_amdgcn_cvt_pkrtz(a, b));
}
__device__ __forceinline__ f32x2 pfma2(f32x2 a, f32x2 b, f32x2 c) {  // v_pk_fma_f32
    return __builtin_elementwise_fma(a, b, c);
}
#define LO2(v) __builtin_shufflevector(v, v, 0, 1)
#define HI2(v) __builtin_shufflevector(v, v, 2, 3)

// h = sigmoid(z1) * tanh( sigmoid(z0) * tanh(z2) ), packed f32, no division.
// sigma = 0.5 + z(1/4 - z^2/48 + z^4/480); tanh = z(1 - z^2/3 + 2z^4/15 - 17z^6/315).
// Same coefficients as v12 (validated: absmax 1.9e-6 after 8192-node mean).
__device__ __forceinline__ f32x2 gate2f(f32x2 z0, f32x2 z1, f32x2 z2) {
    const f32x2 C3 = {-0.33333334f, -0.33333334f};
    const f32x2 C5 = {0.13333334f, 0.13333334f};
    const f32x2 C7 = {-0.05396825f, -0.05396825f};
    const f32x2 Q1 = {0.25f, 0.25f};
    const f32x2 Q3 = {-0.020833334f, -0.020833334f};
    const f32x2 Q5 = {0.0020833334f, 0.0020833334f};
    const f32x2 ONE = {1.f, 1.f}, HALF = {0.5f, 0.5f};
    f32x2 s0 = z0 * z0, s1 = z1 * z1, s2 = z2 * z2;
    f32x2 sg0 = pfma2(z0, pfma2(pfma2(Q5, s0, Q3), s0, Q1), HALF);
    f32x2 sg1 = pfma2(z1, pfma2(pfma2(Q5, s1, Q3), s1, Q1), HALF);
    f32x2 t2  = z2 * pfma2(pfma2(pfma2(C7, s2, C5), s2, C3), s2, ONE);
    f32x2 c   = sg0 * t2;
    f32x2 sc  = c * c;
    f32x2 th  = c * pfma2(pfma2(pfma2(C7, sc, C5), sc, C3), sc, ONE);
    return sg1 * th;
}

// ---------------------------------------------------------------------------
// ws: u16 wfrag[56*512], fid = (mat*4 + wv)*2 + kk
//   lane l elem j = fp16( M[o][k] ), o = wv*16+(l&15), k = 8*(l>>4)+kk*32+j
//   mat0 = W_emb; mat 1+l*3+g = Wx[l][g].
// f32 wbias[7*64] @ byte 57344: mat0 = b_emb, else bW+bU.
// Also zeroes d_out (16KB) so main can atomicAdd (fillBuffer dispatch removed).
// ---------------------------------------------------------------------------
__global__ void prep_weights(const float* __restrict__ W_emb,
                             const float* __restrict__ b_emb,
                             const float* __restrict__ Wx,
                             const float* __restrict__ bW,
                             const float* __restrict__ bU,
                             unsigned short* __restrict__ wfrag,
                             float* __restrict__ wbias,
                             float* __restrict__ outp, int out_size) {
    int t = blockIdx.x * 256 + threadIdx.x;
    if (t < out_size) outp[t] = 0.0f;
    if (t < 448) {
        int mat = t >> 6, o = t & 63;
        wbias[t] = (mat == 0) ? b_emb[o] : (bW[(mat - 1) * 64 + o] + bU[(mat - 1) * 64 + o]);
    }
    if (t < 28672) {
        int j = t & 7, lane = (t >> 3) & 63, fid = t >> 9;
        int kk = fid & 1, wv = (fid >> 1) & 3, mat = fid >> 3;
        int o = wv * 16 + (lane & 15);
        int k = ((lane >> 4) << 3) + kk * 32 + j;
        float v = (mat == 0) ? W_emb[o * 64 + k] : Wx[(mat - 1) * 4096 + o * 64 + k];
        wfrag[t] = f2h(v);
    }
}

// ---------------------------------------------------------------------------
// Main: 2048 blocks x 256 thr, 4 tiles of 64 nodes (batch = blk>>5).
// fp16 planes: element d of row n at u16 idx n*64 + (d ^ ((n&7)<<3)).
// MFMA maps (rounds 2-15 verified): A row o=w*16+(l&15), k=8*(l>>4)+kk*32+j;
// B col n=nt*16+(l&15); C row(dim)=w*16+4*(l>>4)+r, col(node)=nt*16+(l&15).
// Per tile: [convert xp -> x16; prefetch xp(ti+1)] B1 [emb] B2 [L0] B3 [L1].
// ---------------------------------------------------------------------------
__global__ __launch_bounds__(256, 2) void tree_encoder_mfma(
        const float* __restrict__ tree,
        const unsigned short* __restrict__ wfrag,
        const float* __restrict__ wbias,
        float* __restrict__ out) {
    __shared__ unsigned short x16[4096];             // 8 KB, swizzled fp16
    __shared__ unsigned short hA[4096], hB[4096];    // 8+8 KB, swizzled fp16
    const int tid = threadIdx.x;
    const int w = tid >> 6, lane = tid & 63;
    const int lg = lane >> 4, lr = lane & 15;

    // persistent weight A-frags: 7 mats x 2 kk = 14 x s16x8 = 56 VGPR, PINNED
    s16x8 wA[14];
#pragma unroll
    for (int m = 0; m < 7; ++m)
#pragma unroll
        for (int kk = 0; kk < 2; ++kk)
            wA[m * 2 + kk] = *(const s16x8*)(wfrag + (((m * 4 + w) * 2 + kk) << 9) + lane * 8);
#pragma unroll
    for (int m = 0; m < 14; ++m) asm volatile("" : "+v"(wA[m]));  // no remat

    // persistent biases: 7 x f32x4 = 28 VGPR (C rows w*16+4*lg..+3)
    f32x4 bias[7];
#pragma unroll
    for (int m = 0; m < 7; ++m)
        bias[m] = *(const f32x4*)(wbias + m * 64 + w * 16 + 4 * lg);

    // loop-invariant LDS u16-offsets (plane-relative)
    int ro[4][2], wo[4];
#pragma unroll
    for (int nt = 0; nt < 4; ++nt) {
        const int n = nt * 16 + lr, sw = (n & 7) << 3;
        ro[nt][0] = (n << 6) + ((lg << 3) ^ sw);
        ro[nt][1] = (n << 6) + (((lg + 4) << 3) ^ sw);
        wo[nt] = (n << 6) + ((w * 16 + 4 * lg) ^ sw);
    }
    const int nc = tid >> 2;                 // conversion: node within tile
    const int qc = tid & 3;                  // dim quarter (16 floats)
    const int co0 = (nc << 6) + (((2 * qc) ^ (nc & 7)) << 3);
    const int co1 = (nc << 6) + (((2 * qc + 1) ^ (nc & 7)) << 3);

    f32x2 ns01 = {0.f, 0.f}, ns23 = {0.f, 0.f};
    const int t0 = blockIdx.x * 4;

    // prologue: prefetch tile t0 (thread t reads floats [t*16, t*16+16))
    f32x4 xp[4];
    {
        const float* src = tree + ((size_t)t0 << 12) + (tid << 4);
#pragma unroll
        for (int v = 0; v < 4; ++v) xp[v] = *(const f32x4*)(src + 4 * v);
    }

#pragma unroll 1
    for (int ti = 0; ti < 4; ++ti) {
        // ---- convert prefetched x -> swizzled fp16 plane ----
        {
            u32x4 v0, v1;
            v0[0] = pk2(xp[0][0], xp[0][1]); v0[1] = pk2(xp[0][2], xp[0][3]);
            v0[2] = pk2(xp[1][0], xp[1][1]); v0[3] = pk2(xp[1][2], xp[1][3]);
            v1[0] = pk2(xp[2][0], xp[2][1]); v1[1] = pk2(xp[2][2], xp[2][3]);
            v1[2] = pk2(xp[3][0], xp[3][1]); v1[3] = pk2(xp[3][2], xp[3][3]);
            *(u32x4*)&x16[co0] = v0;
            *(u32x4*)&x16[co1] = v1;
        }
        // ---- prefetch next tile (in flight across emb+L0+L1) ----
        if (ti < 3) {
            const float* src = tree + ((size_t)(t0 + ti + 1) << 12) + (tid << 4);
#pragma unroll
            for (int v = 0; v < 4; ++v) xp[v] = *(const f32x4*)(src + 4 * v);
        }
        __syncthreads();  // B1: x16 ready

        // ---- embedding: hA = W_emb @ x + b_emb ----
        {
            f32x4 acc[4];
#pragma unroll
            for (int nt = 0; nt < 4; ++nt) acc[nt] = bias[0];
#pragma unroll
            for (int nt = 0; nt < 4; ++nt)
#pragma unroll
                for (int kk = 0; kk < 2; ++kk) {
                    s16x8 b = *(const s16x8*)&x16[ro[nt][kk]];
                    acc[nt] = __builtin_amdgcn_mfma_f32_16x16x32_f16(wA[kk], b, acc[nt], 0, 0, 0);
                }
#pragma unroll
            for (int nt = 0; nt < 4; ++nt) {
                u32x2 p;
                p[0] = pk2(acc[nt][0], acc[nt][1]);
                p[1] = pk2(acc[nt][2], acc[nt][3]);
                *(u32x2*)&hA[wo[nt]] = p;
            }
        }
        __syncthreads();  // B2: hA ready

        // ---- layer 0: read hA -> packed-f32 gates -> hB ----
        {
#pragma unroll
            for (int nt = 0; nt < 4; ++nt) {
                f32x4 a0 = bias[1], a1 = bias[2], a2 = bias[3];
#pragma unroll
                for (int kk = 0; kk < 2; ++kk) {
                    s16x8 b = *(const s16x8*)&hA[ro[nt][kk]];
                    a0 = __builtin_amdgcn_mfma_f32_16x16x32_f16(wA[2 + kk], b, a0, 0, 0, 0);
                    a1 = __builtin_amdgcn_mfma_f32_16x16x32_f16(wA[4 + kk], b, a1, 0, 0, 0);
                    a2 = __builtin_amdgcn_mfma_f32_16x16x32_f16(wA[6 + kk], b, a2, 0, 0, 0);
                }
                f32x2 h01 = gate2f(LO2(a0), LO2(a1), LO2(a2));
                f32x2 h23 = gate2f(HI2(a0), HI2(a1), HI2(a2));
                u32x2 p;
                p[0] = pk2(h01[0], h01[1]);
                p[1] = pk2(h23[0], h23[1]);
                *(u32x2*)&hB[wo[nt]] = p;
            }
        }
        __syncthreads();  // B3: hB ready

        // ---- layer 1: read hB -> packed-f32 gates -> node-sum (packed) ----
        {
#pragma unroll
            for (int nt = 0; nt < 4; ++nt) {
                f32x4 a0 = bias[4], a1 = bias[5], a2 = bias[6];
#pragma unroll
                for (int kk = 0; kk < 2; ++kk) {
                    s16x8 b = *(const s16x8*)&hB[ro[nt][kk]];
                    a0 = __builtin_amdgcn_mfma_f32_16x16x32_f16(wA[8 + kk], b, a0, 0, 0, 0);
                    a1 = __builtin_amdgcn_mfma_f32_16x16x32_f16(wA[10 + kk], b, a1, 0, 0, 0);
                    a2 = __builtin_amdgcn_mfma_f32_16x16x32_f16(wA[12 + kk], b, a2, 0, 0, 0);
                }
                ns01 += gate2f(LO2(a0), LO2(a1), LO2(a2));
                ns23 += gate2f(HI2(a0), HI2(a1), HI2(a2));
            }
        }
        // x16 rewritten next iter only after all waves passed B3 -> safe.
    }

    // ---- reduce 16 node-columns per lane-group, emit ----
    float nsum[4] = {ns01[0], ns01[1], ns23[0], ns23[1]};
#pragma unroll
    for (int r = 0; r < 4; ++r) {
        float s = nsum[r];
        s += __shfl_xor(s, 1);
        s += __shfl_xor(s, 2);
        s += __shfl_xor(s, 4);
        s += __shfl_xor(s, 8);
        if (lr == 0)
            atomicAdd(&out[(blockIdx.x >> 5) * 64 + w * 16 + 4 * lg + r], s * (1.0f / 8192.0f));
    }
}

extern "C" void kernel_launch(void* const* d_in, const int* in_sizes, int n_in,
                              void* d_out, int out_size, void* d_ws, size_t ws_size,
                              hipStream_t stream) {
    const float* tree  = (const float*)d_in[0];
    const float* W_emb = (const float*)d_in[1];
    const float* b_emb = (const float*)d_in[2];
    const float* Wx    = (const float*)d_in[3];
    const float* bW    = (const float*)d_in[4];
    const float* bU    = (const float*)d_in[5];
    float* outp = (float*)d_out;
    unsigned short* wfrag = (unsigned short*)d_ws;
    float* wbias = (float*)((char*)d_ws + 57344);

    prep_weights<<<112, 256, 0, stream>>>(W_emb, b_emb, Wx, bW, bU, wfrag, wbias,
                                          outp, out_size);
    tree_encoder_mfma<<<2048, 256, 0, stream>>>(tree, wfrag, wbias, outp);
}

// Round 17
// 56.426 us; speedup vs baseline: 1.3098x; 1.0871x over previous
//
#include <hip/hip_runtime.h>
#include <hip/hip_bf16.h>

// TreeEncoder B=64,N=8192,F=H=64,L=2 — fp16 MFMA v17 = v12 (best, 58.5us)
// + d_out zeroing folded into prep_weights (fillBuffer dispatch removed;
// validated in v16). Final configuration:
//  - transposed GEMM Z^T = W @ h^T, weights in 14 pinned VGPR frags
//  - fp16 MFMA 16x16x32, XOR-swizzled LDS planes, 3 barriers/tile
//  - packed-fp16 odd-poly gates (v_pk_fma_f16, division-free)
//  - x reg-prefetch one tile ahead; 2048 blocks x 256 thr.

typedef __attribute__((ext_vector_type(4))) float f32x4;
typedef __attribute__((ext_vector_type(8))) short s16x8;
typedef __attribute__((ext_vector_type(2))) unsigned u32x2;
typedef __attribute__((ext_vector_type(4))) unsigned u32x4;
typedef _Float16 h2 __attribute__((ext_vector_type(2)));

__device__ __forceinline__ unsigned short f2h(float f) {  // RNE f32->fp16
    _Float16 h = (_Float16)f;
    return __builtin_bit_cast(unsigned short, h);
}
__device__ __forceinline__ h2 pkrtz(float a, float b) {   // v_cvt_pkrtz
    return __builtin_bit_cast(h2, __builtin_amdgcn_cvt_pkrtz(a, b));
}
__device__ __forceinline__ unsigned pk2(float a, float b) {
    return __builtin_bit_cast(unsigned, __builtin_amdgcn_cvt_pkrtz(a, b));
}
__device__ __forceinline__ h2 pfma(h2 a, h2 b, h2 c) {    // v_pk_fma_f16
    return __builtin_elementwise_fma(a, b, c);
}
#define H2C(v) h2{(_Float16)(v), (_Float16)(v)}

// h = sigmoid(z1) * tanh( sigmoid(z0) * tanh(z2) ), packed fp16, no division.
__device__ __forceinline__ h2 gate2(h2 z0, h2 z1, h2 z2) {
    const h2 C3 = H2C(-0.33333334f), C5 = H2C(0.13333334f), C7 = H2C(-0.05396825f);
    const h2 Q1 = H2C(0.25f), Q3 = H2C(-0.020833334f), Q5 = H2C(0.0020833334f);
    const h2 ONE = H2C(1.0f), HALF = H2C(0.5f);
    h2 s0 = z0 * z0, s1 = z1 * z1, s2 = z2 * z2;
    h2 sg0 = pfma(z0, pfma(pfma(Q5, s0, Q3), s0, Q1), HALF);
    h2 sg1 = pfma(z1, pfma(pfma(Q5, s1, Q3), s1, Q1), HALF);
    h2 t2  = z2 * pfma(pfma(pfma(C7, s2, C5), s2, C3), s2, ONE);
    h2 c   = sg0 * t2;
    h2 sc  = c * c;
    h2 th  = c * pfma(pfma(pfma(C7, sc, C5), sc, C3), sc, ONE);
    return sg1 * th;
}

// ---------------------------------------------------------------------------
// ws: u16 wfrag[56*512], fid = (mat*4 + wv)*2 + kk
//   lane l elem j = fp16( M[o][k] ), o = wv*16+(l&15), k = 8*(l>>4)+kk*32+j
//   mat0 = W_emb; mat 1+l*3+g = Wx[l][g].
// f32 wbias[7*64] @ byte 57344: mat0 = b_emb, else bW+bU.
// Also zeroes d_out so main can atomicAdd (no separate fill dispatch).
// ---------------------------------------------------------------------------
__global__ void prep_weights(const float* __restrict__ W_emb,
                             const float* __restrict__ b_emb,
                             const float* __restrict__ Wx,
                             const float* __restrict__ bW,
                             const float* __restrict__ bU,
                             unsigned short* __restrict__ wfrag,
                             float* __restrict__ wbias,
                             float* __restrict__ outp, int out_size) {
    int t = blockIdx.x * 256 + threadIdx.x;
    if (t < out_size) outp[t] = 0.0f;
    if (t < 448) {
        int mat = t >> 6, o = t & 63;
        wbias[t] = (mat == 0) ? b_emb[o] : (bW[(mat - 1) * 64 + o] + bU[(mat - 1) * 64 + o]);
    }
    if (t < 28672) {
        int j = t & 7, lane = (t >> 3) & 63, fid = t >> 9;
        int kk = fid & 1, wv = (fid >> 1) & 3, mat = fid >> 3;
        int o = wv * 16 + (lane & 15);
        int k = ((lane >> 4) << 3) + kk * 32 + j;
        float v = (mat == 0) ? W_emb[o * 64 + k] : Wx[(mat - 1) * 4096 + o * 64 + k];
        wfrag[t] = f2h(v);
    }
}

// ---------------------------------------------------------------------------
// Main: 2048 blocks x 256 thr, 4 tiles of 64 nodes (batch = blk>>5).
// fp16 planes: element d of row n at u16 idx n*64 + (d ^ ((n&7)<<3)).
// MFMA maps (rounds 2-16 verified): A row o=w*16+(l&15), k=8*(l>>4)+kk*32+j;
// B col n=nt*16+(l&15); C row(dim)=w*16+4*(l>>4)+r, col(node)=nt*16+(l&15).
// Per tile: [convert xp -> x16; prefetch xp(ti+1)] B1 [emb] B2 [L0] B3 [L1].
// ---------------------------------------------------------------------------
__global__ __launch_bounds__(256, 2) void tree_encoder_mfma(
        const float* __restrict__ tree,
        const unsigned short* __restrict__ wfrag,
        const float* __restrict__ wbias,
        float* __restrict__ out) {
    __shared__ unsigned short x16[4096];             // 8 KB, swizzled fp16
    __shared__ unsigned short hA[4096], hB[4096];    // 8+8 KB, swizzled fp16
    __shared__ float biasL[448];                     // 1.75 KB
    const int tid = threadIdx.x;
    const int w = tid >> 6, lane = tid & 63;
    const int lg = lane >> 4, lr = lane & 15;

    // biases -> LDS (first use is after B1)
    for (int i = tid; i < 448; i += 256) biasL[i] = wbias[i];

    // persistent weight A-frags: 7 mats x 2 kk = 14 x s16x8 = 56 VGPR, PINNED
    s16x8 wA[14];
#pragma unroll
    for (int m = 0; m < 7; ++m)
#pragma unroll
        for (int kk = 0; kk < 2; ++kk)
            wA[m * 2 + kk] = *(const s16x8*)(wfrag + (((m * 4 + w) * 2 + kk) << 9) + lane * 8);
#pragma unroll
    for (int m = 0; m < 14; ++m) asm volatile("" : "+v"(wA[m]));  // no remat

    // loop-invariant LDS u16-offsets (plane-relative)
    int ro[4][2], wo[4];
#pragma unroll
    for (int nt = 0; nt < 4; ++nt) {
        const int n = nt * 16 + lr, sw = (n & 7) << 3;
        ro[nt][0] = (n << 6) + ((lg << 3) ^ sw);
        ro[nt][1] = (n << 6) + (((lg + 4) << 3) ^ sw);
        wo[nt] = (n << 6) + ((w * 16 + 4 * lg) ^ sw);
    }
    const int nc = tid >> 2;                 // conversion: node within tile
    const int qc = tid & 3;                  // dim quarter (16 floats)
    const int co0 = (nc << 6) + (((2 * qc) ^ (nc & 7)) << 3);
    const int co1 = (nc << 6) + (((2 * qc + 1) ^ (nc & 7)) << 3);

    float nsum[4] = {0.f, 0.f, 0.f, 0.f};
    const int t0 = blockIdx.x * 4;

    // prologue: prefetch tile t0 (thread t reads floats [t*16, t*16+16))
    f32x4 xp[4];
    {
        const float* src = tree + ((size_t)t0 << 12) + (tid << 4);
#pragma unroll
        for (int v = 0; v < 4; ++v) xp[v] = *(const f32x4*)(src + 4 * v);
    }

#pragma unroll 1
    for (int ti = 0; ti < 4; ++ti) {
        // ---- convert prefetched x -> swizzled fp16 plane ----
        {
            u32x4 v0, v1;
            v0[0] = pk2(xp[0][0], xp[0][1]); v0[1] = pk2(xp[0][2], xp[0][3]);
            v0[2] = pk2(xp[1][0], xp[1][1]); v0[3] = pk2(xp[1][2], xp[1][3]);
            v1[0] = pk2(xp[2][0], xp[2][1]); v1[1] = pk2(xp[2][2], xp[2][3]);
            v1[2] = pk2(xp[3][0], xp[3][1]); v1[3] = pk2(xp[3][2], xp[3][3]);
            *(u32x4*)&x16[co0] = v0;
            *(u32x4*)&x16[co1] = v1;
        }
        // ---- prefetch next tile (in flight across emb+L0+L1) ----
        if (ti < 3) {
            const float* src = tree + ((size_t)(t0 + ti + 1) << 12) + (tid << 4);
#pragma unroll
            for (int v = 0; v < 4; ++v) xp[v] = *(const f32x4*)(src + 4 * v);
        }
        __syncthreads();  // B1: x16 ready

        // ---- embedding: hA = W_emb @ x + b_emb ----
        {
            const f32x4 be = *(const f32x4*)&biasL[w * 16 + 4 * lg];
            f32x4 acc[4];
#pragma unroll
            for (int nt = 0; nt < 4; ++nt) acc[nt] = be;
#pragma unroll
            for (int nt = 0; nt < 4; ++nt)
#pragma unroll
                for (int kk = 0; kk < 2; ++kk) {
                    s16x8 b = *(const s16x8*)&x16[ro[nt][kk]];
                    acc[nt] = __builtin_amdgcn_mfma_f32_16x16x32_f16(wA[kk], b, acc[nt], 0, 0, 0);
                }
#pragma unroll
            for (int nt = 0; nt < 4; ++nt) {
                u32x2 p;
                p[0] = pk2(acc[nt][0], acc[nt][1]);
                p[1] = pk2(acc[nt][2], acc[nt][3]);
                *(u32x2*)&hA[wo[nt]] = p;
            }
        }
        __syncthreads();  // B2: hA ready

        // ---- layer 0: read hA -> packed gates -> hB ----
        {
            const f32x4 b0 = *(const f32x4*)&biasL[64 + w * 16 + 4 * lg];
            const f32x4 b1 = *(const f32x4*)&biasL[128 + w * 16 + 4 * lg];
            const f32x4 b2 = *(const f32x4*)&biasL[192 + w * 16 + 4 * lg];
#pragma unroll
            for (int nt = 0; nt < 4; ++nt) {
                f32x4 a0 = b0, a1 = b1, a2 = b2;
#pragma unroll
                for (int kk = 0; kk < 2; ++kk) {
                    s16x8 b = *(const s16x8*)&hA[ro[nt][kk]];
                    a0 = __builtin_amdgcn_mfma_f32_16x16x32_f16(wA[2 + kk], b, a0, 0, 0, 0);
                    a1 = __builtin_amdgcn_mfma_f32_16x16x32_f16(wA[4 + kk], b, a1, 0, 0, 0);
                    a2 = __builtin_amdgcn_mfma_f32_16x16x32_f16(wA[6 + kk], b, a2, 0, 0, 0);
                }
                h2 hlo = gate2(pkrtz(a0[0], a0[1]), pkrtz(a1[0], a1[1]), pkrtz(a2[0], a2[1]));
                h2 hhi = gate2(pkrtz(a0[2], a0[3]), pkrtz(a1[2], a1[3]), pkrtz(a2[2], a2[3]));
                u32x2 p;
                p[0] = __builtin_bit_cast(unsigned, hlo);
                p[1] = __builtin_bit_cast(unsigned, hhi);
                *(u32x2*)&hB[wo[nt]] = p;
            }
        }
        __syncthreads();  // B3: hB ready

        // ---- layer 1: read hB -> packed gates -> node-sum ----
        {
            const f32x4 b0 = *(const f32x4*)&biasL[256 + w * 16 + 4 * lg];
            const f32x4 b1 = *(const f32x4*)&biasL[320 + w * 16 + 4 * lg];
            const f32x4 b2 = *(const f32x4*)&biasL[384 + w * 16 + 4 * lg];
#pragma unroll
            for (int nt = 0; nt < 4; ++nt) {
                f32x4 a0 = b0, a1 = b1, a2 = b2;
#pragma unroll
                for (int kk = 0; kk < 2; ++kk) {
                    s16x8 b = *(const s16x8*)&hB[ro[nt][kk]];
                    a0 = __builtin_amdgcn_mfma_f32_16x16x32_f16(wA[8 + kk], b, a0, 0, 0, 0);
                    a1 = __builtin_amdgcn_mfma_f32_16x16x32_f16(wA[10 + kk], b, a1, 0, 0, 0);
                    a2 = __builtin_amdgcn_mfma_f32_16x16x32_f16(wA[12 + kk], b, a2, 0, 0, 0);
                }
                h2 hlo = gate2(pkrtz(a0[0], a0[1]), pkrtz(a1[0], a1[1]), pkrtz(a2[0], a2[1]));
                h2 hhi = gate2(pkrtz(a0[2], a0[3]), pkrtz(a1[2], a1[3]), pkrtz(a2[2], a2[3]));
                nsum[0] += (float)hlo[0];
                nsum[1] += (float)hlo[1];
                nsum[2] += (float)hhi[0];
                nsum[3] += (float)hhi[1];
            }
        }
        // x16 rewritten next iter only after all waves passed B3 -> safe.
    }

    // ---- reduce 16 node-columns per lane-group, emit ----
#pragma unroll
    for (int r = 0; r < 4; ++r) {
        float s = nsum[r];
        s += __shfl_xor(s, 1);
        s += __shfl_xor(s, 2);
        s += __shfl_xor(s, 4);
        s += __shfl_xor(s, 8);
        if (lr == 0)
            atomicAdd(&out[(blockIdx.x >> 5) * 64 + w * 16 + 4 * lg + r], s * (1.0f / 8192.0f));
    }
}

extern "C" void kernel_launch(void* const* d_in, const int* in_sizes, int n_in,
                              void* d_out, int out_size, void* d_ws, size_t ws_size,
                              hipStream_t stream) {
    const float* tree  = (const float*)d_in[0];
    const float* W_emb = (const float*)d_in[1];
    const float* b_emb = (const float*)d_in[2];
    const float* Wx    = (const float*)d_in[3];
    const float* bW    = (const float*)d_in[4];
    const float* bU    = (const float*)d_in[5];
    float* outp = (float*)d_out;
    unsigned short* wfrag = (unsigned short*)d_ws;
    float* wbias = (float*)((char*)d_ws + 57344);

    prep_weights<<<112, 256, 0, stream>>>(W_emb, b_emb, Wx, bW, bU, wfrag, wbias,
                                          outp, out_size);
    tree_encoder_mfma<<<2048, 256, 0, stream>>>(tree, wfrag, wbias, outp);
}